// Round 1
// baseline (300.395 us; speedup 1.0000x reference)
//
#include <hip/hip_runtime.h>

// PathBundleChoiceScorer — reduced computation:
//   t1 = tanh(x @ W1^T)            [4096,1024] = [4096,1024]x[1024,1024]^T
//   t2 = tanh(t1 @ W2^T)           [4096,1024]
//   s[n] = dot(t2[n,:], Wout)      per-row scalar
//   out[n] = top9-weighted collapse of {c_j * s}, c in {-1,0,+1} fixed pattern,
//            scores f(c*s) with f = sob_w . sin(2pi/7 (soa_w v + soa_b)) + sob_b
// Layer-1/-2 scorer weights (d_in[4..11]) are dead code (no pruning until 27 paths).

#define BM 128
#define BN 128
#define BK 16

__global__ __launch_bounds__(256, 2)
void pbcs_gemm_bt_tanh(const float* __restrict__ A, const float* __restrict__ B,
                       float* __restrict__ C, int M, int N, int K)
{
    __shared__ float As[BK][BM];
    __shared__ float Bs[BK][BN];

    const int tid = threadIdx.x;
    const int tx  = tid & 15;       // 0..15 -> output col group
    const int ty  = tid >> 4;       // 0..15 -> output row group
    const int bn  = blockIdx.x;
    const int bm  = blockIdx.y;

    // staging assignment: thread -> (tile row lr, col offset lh = 0 or 8)
    const int lr = tid >> 1;
    const int lh = (tid & 1) * 8;

    const float* pA = A + (size_t)(bm * BM + lr) * K + lh;
    const float* pB = B + (size_t)(bn * BN + lr) * K + lh;

    float acc[8][8];
#pragma unroll
    for (int i = 0; i < 8; ++i)
#pragma unroll
        for (int j = 0; j < 8; ++j) acc[i][j] = 0.f;

    for (int k0 = 0; k0 < K; k0 += BK) {
        float4 a0 = *(const float4*)(pA + k0);
        float4 a1 = *(const float4*)(pA + k0 + 4);
        float4 b0 = *(const float4*)(pB + k0);
        float4 b1 = *(const float4*)(pB + k0 + 4);
        __syncthreads();   // previous compute phase done before overwrite
        As[lh + 0][lr] = a0.x; As[lh + 1][lr] = a0.y;
        As[lh + 2][lr] = a0.z; As[lh + 3][lr] = a0.w;
        As[lh + 4][lr] = a1.x; As[lh + 5][lr] = a1.y;
        As[lh + 6][lr] = a1.z; As[lh + 7][lr] = a1.w;
        Bs[lh + 0][lr] = b0.x; Bs[lh + 1][lr] = b0.y;
        Bs[lh + 2][lr] = b0.z; Bs[lh + 3][lr] = b0.w;
        Bs[lh + 4][lr] = b1.x; Bs[lh + 5][lr] = b1.y;
        Bs[lh + 6][lr] = b1.z; Bs[lh + 7][lr] = b1.w;
        __syncthreads();
#pragma unroll
        for (int k = 0; k < BK; ++k) {
            float a[8], b[8];
            *(float4*)(a)     = *(const float4*)&As[k][ty * 4];
            *(float4*)(a + 4) = *(const float4*)&As[k][ty * 4 + 64];
            *(float4*)(b)     = *(const float4*)&Bs[k][tx * 4];
            *(float4*)(b + 4) = *(const float4*)&Bs[k][tx * 4 + 64];
#pragma unroll
            for (int i = 0; i < 8; ++i)
#pragma unroll
                for (int j = 0; j < 8; ++j)
                    acc[i][j] = fmaf(a[i], b[j], acc[i][j]);
        }
    }

    // epilogue: tanh + float4 stores
#pragma unroll
    for (int i = 0; i < 8; ++i) {
        const int mrow = bm * BM + ty * 4 + (i & 3) + ((i >> 2) * 64);
        float4 o0, o1;
        o0.x = tanhf(acc[i][0]); o0.y = tanhf(acc[i][1]);
        o0.z = tanhf(acc[i][2]); o0.w = tanhf(acc[i][3]);
        o1.x = tanhf(acc[i][4]); o1.y = tanhf(acc[i][5]);
        o1.z = tanhf(acc[i][6]); o1.w = tanhf(acc[i][7]);
        *(float4*)(C + (size_t)mrow * N + bn * BN + tx * 4)      = o0;
        *(float4*)(C + (size_t)mrow * N + bn * BN + 64 + tx * 4) = o1;
    }
}

// One wave per row: s = dot(t2_row, wout); then faithful 27-element top-9 collapse.
__global__ __launch_bounds__(256)
void pbcs_finalize(const float* __restrict__ t2, const float* __restrict__ wout,
                   const float* __restrict__ soa_w, const float* __restrict__ soa_b,
                   const float* __restrict__ sob_w, const float* __restrict__ sob_b,
                   float* __restrict__ out, int Nrows, int H)
{
    const int gid  = blockIdx.x * blockDim.x + threadIdx.x;
    const int row  = gid >> 6;
    const int lane = threadIdx.x & 63;
    if (row >= Nrows) return;

    const float* r = t2 + (size_t)row * H;
    float part = 0.f;
    for (int w = lane * 4; w < H; w += 256) {
        float4 v = *(const float4*)(r + w);
        float4 g = *(const float4*)(wout + w);
        part = fmaf(v.x, g.x, part);
        part = fmaf(v.y, g.y, part);
        part = fmaf(v.z, g.z, part);
        part = fmaf(v.w, g.w, part);
    }
#pragma unroll
    for (int off = 32; off > 0; off >>= 1) part += __shfl_xor(part, off, 64);
    const float s = __shfl(part, 0, 64);

    // f(s), f(0), f(-s): distribute the 32 hidden terms over lanes 0..31
    const float C7 = 0.8975979010256552f;   // 2*pi/7
    float tS = 0.f, tZ = 0.f, tN = 0.f;
    if (lane < 32) {
        const float aw = soa_w[lane];
        const float ab = soa_b[lane];
        const float bw = sob_w[lane];
        tS = bw * __sinf(0.f) ; // placeholder avoided below
        tS = bw * sinf(C7 * fmaf(aw,  s, ab));
        tZ = bw * sinf(C7 * ab);
        tN = bw * sinf(C7 * fmaf(aw, -s, ab));
    }
#pragma unroll
    for (int off = 32; off > 0; off >>= 1) {
        tS += __shfl_xor(tS, off, 64);
        tZ += __shfl_xor(tZ, off, 64);
        tN += __shfl_xor(tN, off, 64);
    }
    const float bb = sob_b[0];
    const float fS = __shfl(tS, 0, 64) + bb;
    const float f0 = __shfl(tZ, 0, 64) + bb;
    const float fN = __shfl(tN, 0, 64) + bb;

    // 27 path values: j = k*3+q, pos3 pattern P[k] = {1,0,-1,0,0,0,-1,0,1},
    // tri order q: (-pos, 0, +pos)  ->  coefficient c = q==0 ? -P : q==2 ? P : 0
    const int j  = lane;               // lanes 0..26 own one path entry
    const int kk = j / 3;
    const int q  = j - kk * 3;
    const int p  = ((0x101 >> kk) & 1) - ((0x044 >> kk) & 1);   // P[k]
    const int c  = (q == 0) ? -p : ((q == 2) ? p : 0);
    const float val = (float)c * s;
    const float sc  = (c == 0) ? f0 : ((c > 0) ? fS : fN);

    // stable top-9 membership (jax.lax.top_k tie-break: lower index first)
    int rank = 0;
#pragma unroll 1
    for (int i = 0; i < 27; ++i) {
        const float sci = __shfl(sc, i, 64);
        rank += (sci > sc) || (sci == sc && i < j);
    }
    const float mx = fmaxf(fS, fmaxf(f0, fN));
    float e = (j < 27 && rank < 9) ? expf(sc - mx) : 0.f;
    float num = val * e;
    float den = e;
#pragma unroll
    for (int off = 32; off > 0; off >>= 1) {
        num += __shfl_xor(num, off, 64);
        den += __shfl_xor(den, off, 64);
    }
    if (lane == 0) out[row] = num / den;
}

extern "C" void kernel_launch(void* const* d_in, const int* in_sizes, int n_in,
                              void* d_out, int out_size, void* d_ws, size_t ws_size,
                              hipStream_t stream)
{
    const float* x     = (const float*)d_in[0];
    const float* W1    = (const float*)d_in[1];
    const float* W2    = (const float*)d_in[2];
    const float* Wout  = (const float*)d_in[3];
    const float* soa_w = (const float*)d_in[12];
    const float* soa_b = (const float*)d_in[13];
    const float* sob_w = (const float*)d_in[14];
    const float* sob_b = (const float*)d_in[15];

    const int Nr = 4096, D = 1024, H = 1024;  // fixed problem shape
    float* t1 = (float*)d_ws;                 // 16 MB
    float* t2 = t1 + (size_t)Nr * H;          // 16 MB

    dim3 g1(H / BN, Nr / BM);                 // (8, 32) = 256 blocks
    pbcs_gemm_bt_tanh<<<g1, 256, 0, stream>>>(x,  W1, t1, Nr, H, D);
    pbcs_gemm_bt_tanh<<<g1, 256, 0, stream>>>(t1, W2, t2, Nr, H, H);

    const int waves = Nr;                     // one wave per row
    pbcs_finalize<<<(waves * 64) / 256, 256, 0, stream>>>(
        t2, Wout, soa_w, soa_b, sob_w, sob_b, (float*)d_out, Nr, H);
}

// Round 2
// 94.613 us; speedup vs baseline: 3.1750x; 3.1750x over previous
//
#include <hip/hip_runtime.h>

// PathBundleChoiceScorer — reduced computation (verified round 1):
//   t1 = tanh(x @ W1^T); t2 = tanh(t1 @ W2^T); s[n] = dot(t2[n,:], Wout)
//   out[n] = top9-weighted collapse of {c_j*s}, c fixed {-1,0,+1} pattern.
// Round 2: GEMMs via bf16 MFMA with hi/lo split (3 products, lo*lo dropped,
// error ~3*2^-16 rel per product ≈ f32-chain level). A staged f32 via
// global_load_lds (split at read), B pre-split bf16 hi/lo via global_load_lds.

typedef __attribute__((ext_vector_type(4))) float  f32x4;
typedef __attribute__((ext_vector_type(8))) short  short8;

#define AS1 __attribute__((address_space(1)))
#define AS3 __attribute__((address_space(3)))
#define GLOAD16(gp, lp) \
    __builtin_amdgcn_global_load_lds((AS1 const void*)(gp), (AS3 void*)(lp), 16, 0, 0)

// ---- split f32 -> bf16 hi/lo ------------------------------------------------
__global__ __launch_bounds__(256)
void pbcs_split(const float* __restrict__ w, unsigned short* __restrict__ hi,
                unsigned short* __restrict__ lo)
{
    const int i = blockIdx.x * 256 + threadIdx.x;   // handles 4 f32
    float4 v = ((const float4*)w)[i];
    ushort4 h, l;
    float vv[4] = {v.x, v.y, v.z, v.w};
    unsigned short hh[4], ll[4];
#pragma unroll
    for (int e = 0; e < 4; ++e) {
        __bf16 hb = (__bf16)vv[e];
        hh[e] = __builtin_bit_cast(unsigned short, hb);
        float hf = (float)hb;
        __bf16 lb = (__bf16)(vv[e] - hf);
        ll[e] = __builtin_bit_cast(unsigned short, lb);
    }
    h.x = hh[0]; h.y = hh[1]; h.z = hh[2]; h.w = hh[3];
    l.x = ll[0]; l.y = ll[1]; l.z = ll[2]; l.w = ll[3];
    ((ushort4*)hi)[i] = h;
    ((ushort4*)lo)[i] = l;
}

// ---- split-bf16 MFMA GEMM:  C = tanh(A @ B^T) or fused s-dot ---------------
// A: [4096,1024] f32 (x or t1).  Bhi/Blo: [1024,1024] bf16 (split W).
// BM=64, BN=128, BK=32, 256 threads (4 waves, 2m x 2n), per-wave 32x64.
// EPI=0: write tanh -> t1out f32.  EPI=1: s_part[row*16 + bn*2 + wn] = partial dot.
template<int EPI>
__global__ __launch_bounds__(256, 2)
void pbcs_gemm_split(const float* __restrict__ A,
                     const unsigned short* __restrict__ Bhi,
                     const unsigned short* __restrict__ Blo,
                     float* __restrict__ t1out,
                     const float* __restrict__ wout,
                     float* __restrict__ s_part)
{
    __shared__ char smem[2][24576];   // [buf][ A f32 8K | Bhi 8K | Blo 8K ]

    const int tid  = threadIdx.x;
    const int lane = tid & 63;
    const int wid  = tid >> 6;
    const int wm   = wid >> 1;        // 0..1 -> 32-row half
    const int wn   = wid & 1;         // 0..1 -> 64-col half
    const int l15  = lane & 15;
    const int g    = lane >> 4;       // k-group 0..3
    const int bm   = blockIdx.y;      // 64 rows / block
    const int bn   = blockIdx.x;      // 128 cols / block

    // ---- staging source pointers + LDS dest offsets (t-independent) ----
    // A chunks (f32 tile 64x32 = 8KB, 8 chunks of 1KB): c = wid*2 + j
    const float* aS0; const float* aS1; int aD0, aD1;
    {
        int c = wid * 2, r = c * 8 + (lane >> 3);
        int p = (lane & 7) >> 1, e = lane & 1;
        aS0 = A + (size_t)(bm * 64 + r) * 1024 + 8 * (p ^ (r & 3)) + 4 * e;
        aD0 = c * 1024;
        c = wid * 2 + 1; r = c * 8 + (lane >> 3);
        aS1 = A + (size_t)(bm * 64 + r) * 1024 + 8 * (p ^ (r & 3)) + 4 * e;
        aD1 = c * 1024;
    }
    // B chunks (hi 8KB: c 0..7, lo 8KB: c 8..15): c = wid*4 + j
    const unsigned short* bS[4]; int bD[4];
#pragma unroll
    for (int j = 0; j < 4; ++j) {
        int c = wid * 4 + j;
        int r = (c & 7) * 16 + (lane >> 2);
        int s = lane & 3;
        const unsigned short* base = (c < 8) ? Bhi : Blo;
        bS[j] = base + (size_t)(bn * 128 + r) * 1024 + 8 * (s ^ (r & 3));
        bD[j] = 8192 + ((c < 8) ? 0 : 8192) + (c & 7) * 1024;
    }
    const unsigned short* bS0 = bS[0]; const unsigned short* bS1 = bS[1];
    const unsigned short* bS2 = bS[2]; const unsigned short* bS3 = bS[3];
    const int bD0 = bD[0], bD1 = bD[1], bD2 = bD[2], bD3 = bD[3];

    // ---- LDS read offsets (swizzled, t-independent) ----
    int aoff0, aoff1, boff[4];
    {
        int r0 = wm * 32 + l15;        aoff0 = r0 * 128 + 32 * (g ^ (r0 & 3));
        int r1 = wm * 32 + 16 + l15;   aoff1 = r1 * 128 + 32 * (g ^ (r1 & 3));
#pragma unroll
        for (int nf = 0; nf < 4; ++nf) {
            int r = wn * 64 + nf * 16 + l15;
            boff[nf] = r * 64 + 16 * (g ^ (r & 3));
        }
    }
    const int boff0 = boff[0], boff1 = boff[1], boff2 = boff[2], boff3 = boff[3];

    f32x4 acc[2][4];
#pragma unroll
    for (int i = 0; i < 2; ++i)
#pragma unroll
        for (int j = 0; j < 4; ++j) acc[i][j] = (f32x4)0.f;

#define STAGE(buf, kt) do {                                   \
        GLOAD16(aS0 + (kt) * 32, smem[buf] + aD0);            \
        GLOAD16(aS1 + (kt) * 32, smem[buf] + aD1);            \
        GLOAD16(bS0 + (kt) * 32, smem[buf] + bD0);            \
        GLOAD16(bS1 + (kt) * 32, smem[buf] + bD1);            \
        GLOAD16(bS2 + (kt) * 32, smem[buf] + bD2);            \
        GLOAD16(bS3 + (kt) * 32, smem[buf] + bD3);            \
    } while (0)

#define COMPUTE(buf) do {                                                         \
        const char* _Ab = smem[buf];                                              \
        const char* _Bh = smem[buf] + 8192;                                       \
        const char* _Bl = smem[buf] + 16384;                                      \
        f32x4 _a0[2], _a1[2];                                                     \
        short8 _bh[4], _bl[4];                                                    \
        _a0[0] = *(const f32x4*)(_Ab + aoff0);                                    \
        _a1[0] = *(const f32x4*)(_Ab + aoff0 + 16);                               \
        _a0[1] = *(const f32x4*)(_Ab + aoff1);                                    \
        _a1[1] = *(const f32x4*)(_Ab + aoff1 + 16);                               \
        _bh[0] = *(const short8*)(_Bh + boff0); _bl[0] = *(const short8*)(_Bl + boff0); \
        _bh[1] = *(const short8*)(_Bh + boff1); _bl[1] = *(const short8*)(_Bl + boff1); \
        _bh[2] = *(const short8*)(_Bh + boff2); _bl[2] = *(const short8*)(_Bl + boff2); \
        _bh[3] = *(const short8*)(_Bh + boff3); _bl[3] = *(const short8*)(_Bl + boff3); \
        short8 _ah[2], _al[2];                                                    \
        _Pragma("unroll")                                                         \
        for (int mf = 0; mf < 2; ++mf) {                                          \
            float _va[8];                                                         \
            *(f32x4*)_va = _a0[mf]; *(f32x4*)(_va + 4) = _a1[mf];                 \
            _Pragma("unroll")                                                     \
            for (int e = 0; e < 8; ++e) {                                         \
                float _v = _va[e];                                                \
                __bf16 _h = (__bf16)_v;                                           \
                _ah[mf][e] = __builtin_bit_cast(short, _h);                       \
                float _hf = (float)_h;                                            \
                _al[mf][e] = __builtin_bit_cast(short, (__bf16)(_v - _hf));       \
            }                                                                     \
        }                                                                         \
        _Pragma("unroll")                                                         \
        for (int mf = 0; mf < 2; ++mf)                                            \
        _Pragma("unroll")                                                         \
        for (int nf = 0; nf < 4; ++nf) {                                          \
            acc[mf][nf] = __builtin_amdgcn_mfma_f32_16x16x32_bf16(_ah[mf], _bh[nf], acc[mf][nf], 0, 0, 0); \
            acc[mf][nf] = __builtin_amdgcn_mfma_f32_16x16x32_bf16(_al[mf], _bh[nf], acc[mf][nf], 0, 0, 0); \
            acc[mf][nf] = __builtin_amdgcn_mfma_f32_16x16x32_bf16(_ah[mf], _bl[nf], acc[mf][nf], 0, 0, 0); \
        }                                                                         \
    } while (0)

    STAGE(0, 0);
    __syncthreads();
#pragma unroll 1
    for (int t = 0; t < 30; t += 2) {
        STAGE(1, t + 1);
        COMPUTE(0);
        __syncthreads();
        STAGE(0, t + 2);
        COMPUTE(1);
        __syncthreads();
    }
    STAGE(1, 31);
    COMPUTE(0);
    __syncthreads();
    COMPUTE(1);

    // ---- epilogue ----
    if (EPI == 0) {
        // t1 = tanh(acc), f32, scalar stores (64B contiguous per 16 lanes)
#pragma unroll
        for (int mf = 0; mf < 2; ++mf)
#pragma unroll
        for (int nf = 0; nf < 4; ++nf)
#pragma unroll
        for (int j = 0; j < 4; ++j) {
            int row = bm * 64 + wm * 32 + mf * 16 + g * 4 + j;
            int col = bn * 128 + wn * 64 + nf * 16 + l15;
            t1out[(size_t)row * 1024 + col] = tanhf(acc[mf][nf][j]);
        }
    } else {
        // fused s-dot: partial = sum_cols tanh(t2)*wout[col], reduce 16 lanes
        float w[4];
#pragma unroll
        for (int nf = 0; nf < 4; ++nf)
            w[nf] = wout[bn * 128 + wn * 64 + nf * 16 + l15];
#pragma unroll
        for (int mf = 0; mf < 2; ++mf)
#pragma unroll
        for (int j = 0; j < 4; ++j) {
            float v = 0.f;
#pragma unroll
            for (int nf = 0; nf < 4; ++nf)
                v += tanhf(acc[mf][nf][j]) * w[nf];
            v += __shfl_xor(v, 1, 64);
            v += __shfl_xor(v, 2, 64);
            v += __shfl_xor(v, 4, 64);
            v += __shfl_xor(v, 8, 64);
            if (l15 == 0) {
                int row = bm * 64 + wm * 32 + mf * 16 + g * 4 + j;
                s_part[row * 16 + bn * 2 + wn] = v;
            }
        }
    }
#undef STAGE
#undef COMPUTE
}

// ---- finalize: s = sum(s_part), then faithful 27-path top-9 collapse -------
__global__ __launch_bounds__(256)
void pbcs_finalize(const float* __restrict__ s_part,
                   const float* __restrict__ soa_w, const float* __restrict__ soa_b,
                   const float* __restrict__ sob_w, const float* __restrict__ sob_b,
                   float* __restrict__ out, int Nrows)
{
    const int row  = blockIdx.x * 4 + (threadIdx.x >> 6);
    const int lane = threadIdx.x & 63;
    if (row >= Nrows) return;

    float part = (lane < 16) ? s_part[row * 16 + lane] : 0.f;
#pragma unroll
    for (int off = 32; off > 0; off >>= 1) part += __shfl_xor(part, off, 64);
    const float s = part;

    const float C7 = 0.8975979010256552f;   // 2*pi/7
    float tS = 0.f, tZ = 0.f, tN = 0.f;
    if (lane < 32) {
        const float aw = soa_w[lane];
        const float ab = soa_b[lane];
        const float bw = sob_w[lane];
        tS = bw * sinf(C7 * fmaf(aw,  s, ab));
        tZ = bw * sinf(C7 * ab);
        tN = bw * sinf(C7 * fmaf(aw, -s, ab));
    }
#pragma unroll
    for (int off = 32; off > 0; off >>= 1) {
        tS += __shfl_xor(tS, off, 64);
        tZ += __shfl_xor(tZ, off, 64);
        tN += __shfl_xor(tN, off, 64);
    }
    const float bb = sob_b[0];
    const float fS = tS + bb;
    const float f0 = tZ + bb;
    const float fN = tN + bb;

    // 27 paths: P[k] = {1,0,-1,0,0,0,-1,0,1}; tri q: (-pos, 0, +pos)
    const int j  = lane;
    const int kk = j / 3;
    const int q  = j - kk * 3;
    const int p  = ((0x101 >> kk) & 1) - ((0x044 >> kk) & 1);
    const int c  = (q == 0) ? -p : ((q == 2) ? p : 0);
    const float val = (float)c * s;
    const float sc  = (c == 0) ? f0 : ((c > 0) ? fS : fN);

    int rank = 0;
#pragma unroll 1
    for (int i = 0; i < 27; ++i) {
        const float sci = __shfl(sc, i, 64);
        rank += (sci > sc) || (sci == sc && i < j);
    }
    const float mx = fmaxf(fS, fmaxf(f0, fN));
    float e = (j < 27 && rank < 9) ? expf(sc - mx) : 0.f;
    float num = val * e;
    float den = e;
#pragma unroll
    for (int off = 32; off > 0; off >>= 1) {
        num += __shfl_xor(num, off, 64);
        den += __shfl_xor(den, off, 64);
    }
    if (lane == 0) out[row] = num / den;
}

extern "C" void kernel_launch(void* const* d_in, const int* in_sizes, int n_in,
                              void* d_out, int out_size, void* d_ws, size_t ws_size,
                              hipStream_t stream)
{
    const float* x     = (const float*)d_in[0];
    const float* W1    = (const float*)d_in[1];
    const float* W2    = (const float*)d_in[2];
    const float* Wout  = (const float*)d_in[3];
    const float* soa_w = (const float*)d_in[12];
    const float* soa_b = (const float*)d_in[13];
    const float* sob_w = (const float*)d_in[14];
    const float* sob_b = (const float*)d_in[15];

    const int Nr = 4096;
    char* ws = (char*)d_ws;
    unsigned short* W1hi = (unsigned short*)ws;                  // 2MB each
    unsigned short* W1lo = W1hi + (1u << 20);
    unsigned short* W2hi = W1hi + (2u << 20);
    unsigned short* W2lo = W1hi + (3u << 20);
    float* t1     = (float*)(ws + (8u << 20));                   // 16MB
    float* s_part = (float*)(ws + (24u << 20));                  // 256KB

    pbcs_split<<<1024, 256, 0, stream>>>(W1, W1hi, W1lo);
    pbcs_split<<<1024, 256, 0, stream>>>(W2, W2hi, W2lo);

    dim3 grid(8, 64);   // (N/128, M/64) = 512 blocks
    pbcs_gemm_split<0><<<grid, 256, 0, stream>>>(x,  W1hi, W1lo, t1, nullptr, nullptr);
    pbcs_gemm_split<1><<<grid, 256, 0, stream>>>(t1, W2hi, W2lo, nullptr, Wout, s_part);

    pbcs_finalize<<<Nr / 4, 256, 0, stream>>>(s_part, soa_w, soa_b, sob_w, sob_b,
                                              (float*)d_out, Nr);
}

// Round 3
// 92.147 us; speedup vs baseline: 3.2600x; 1.0268x over previous
//
#include <hip/hip_runtime.h>

// PathBundleChoiceScorer — reduced computation (verified rounds 1-2):
//   t1 = tanh(x @ W1^T); t2 = tanh(t1 @ W2^T); s[n] = dot(t2[n,:], Wout)
//   out[n] = top9-weighted collapse of {c_j*s}, c fixed {-1,0,+1} pattern.
// Round 3: 2-way-free LDS swizzles, t1 stored as bf16 hi/lo (GEMM2 pure-bf16),
// triple-buffered counted-vmcnt pipeline (stage t+2, vmcnt(6), raw s_barrier).

typedef __attribute__((ext_vector_type(4))) float  f32x4;
typedef __attribute__((ext_vector_type(8))) short  short8;

#define AS1 __attribute__((address_space(1)))
#define AS3 __attribute__((address_space(3)))
#define GLOAD16(gp, lp) \
    __builtin_amdgcn_global_load_lds((AS1 const void*)(gp), (AS3 void*)(lp), 16, 0, 0)

// ---- split f32 -> bf16 hi/lo ------------------------------------------------
__global__ __launch_bounds__(256)
void pbcs_split(const float* __restrict__ w, unsigned short* __restrict__ hi,
                unsigned short* __restrict__ lo)
{
    const int i = blockIdx.x * 256 + threadIdx.x;   // handles 4 f32
    float4 v = ((const float4*)w)[i];
    float vv[4] = {v.x, v.y, v.z, v.w};
    unsigned short hh[4], ll[4];
#pragma unroll
    for (int e = 0; e < 4; ++e) {
        __bf16 hb = (__bf16)vv[e];
        hh[e] = __builtin_bit_cast(unsigned short, hb);
        __bf16 lb = (__bf16)(vv[e] - (float)hb);
        ll[e] = __builtin_bit_cast(unsigned short, lb);
    }
    ushort4 h = {hh[0], hh[1], hh[2], hh[3]};
    ushort4 l = {ll[0], ll[1], ll[2], ll[3]};
    ((ushort4*)hi)[i] = h;
    ((ushort4*)lo)[i] = l;
}

// ---- split-bf16 MFMA GEMM ---------------------------------------------------
// BM=64, BN=128, BK=32, 256 threads (4 waves 2x2), wave tile 32x64.
// ASPLIT=1: A is f32 (x), split to bf16 hi/lo in registers.
// ASPLIT=0: A is pre-split bf16 hi/lo (t1hi/t1lo).
// EPI=0: store tanh(acc) as bf16 hi/lo.  EPI=1: fused s-dot partials.
template<int ASPLIT, int EPI>
__global__ __launch_bounds__(256, 2)
void pbcs_gemm(const float* __restrict__ Af32,
               const unsigned short* __restrict__ Ahi,
               const unsigned short* __restrict__ Alo,
               const unsigned short* __restrict__ Bhi,
               const unsigned short* __restrict__ Blo,
               unsigned short* __restrict__ Chi,
               unsigned short* __restrict__ Clo,
               const float* __restrict__ wout,
               float* __restrict__ s_part)
{
    // buffer layout: [A 8K (f32) | Bhi 8K | Blo 8K]  or  [Ahi 4K | Alo 4K | Bhi | Blo]
    __shared__ char smem[3][24576];

    const int tid  = threadIdx.x;
    const int lane = tid & 63;
    const int wid  = tid >> 6;
    const int wm   = wid >> 1;
    const int wn   = wid & 1;
    const int l15  = lane & 15;
    const int g    = lane >> 4;
    const int bm   = blockIdx.y;
    const int bn   = blockIdx.x;

    // ---- staging: 24 chunks of 1KB, 6 per wave; linear LDS dest, pre-swizzled src
    const char* sp[6];   // global src (per-lane, swizzled)
    int         sd[6];   // LDS dest byte offset (wave-uniform base)
    int         st[6];   // per-k-tile byte stride
#pragma unroll
    for (int j = 0; j < 6; ++j) {
        const int c = wid * 6 + j;
        if (c >= 8) {
            // B chunks: 16 rows x 64B; cc 0..7 Bhi, 8..15 Blo
            const int cc = c - 8;
            const int r  = lane >> 2, s = lane & 3;
            const int row = (cc & 7) * 16 + r;
            const int pi = (r >> 1) & 3;
            const unsigned short* base = (cc < 8) ? Bhi : Blo;
            sp[j] = (const char*)(base + (size_t)(bn * 128 + row) * 1024 + 8 * (s ^ pi));
            sd[j] = 8192 + ((cc < 8) ? 0 : 8192) + (cc & 7) * 1024;
            st[j] = 64;
        } else if (ASPLIT) {
            // A f32 chunks: 8 rows x 128B
            const int r = lane >> 3, s = lane & 7;
            const int row = c * 8 + r;
            const int pi = ((r >> 1) & 3) | ((r & 1) << 2);
            sp[j] = (const char*)(Af32 + (size_t)(bm * 64 + row) * 1024 + 4 * (s ^ pi));
            sd[j] = c * 1024;
            st[j] = 128;
        } else {
            // A bf16 chunks: 16 rows x 64B; c 0..3 Ahi, 4..7 Alo
            const int r = lane >> 2, s = lane & 3;
            const int row = (c & 3) * 16 + r;
            const int pi = (r >> 1) & 3;
            const unsigned short* base = (c < 4) ? Ahi : Alo;
            sp[j] = (const char*)(base + (size_t)(bm * 64 + row) * 1024 + 8 * (s ^ pi));
            sd[j] = ((c < 4) ? 0 : 4096) + (c & 3) * 1024;
            st[j] = 64;
        }
    }

    // ---- LDS read offsets (2-way-free swizzled) ----
    const int pi4 = (l15 >> 1) & 3;
    const int pi8 = pi4 | ((l15 & 1) << 2);
    int aoffX[2][2], aoffH[2], boff[4];
#pragma unroll
    for (int mf = 0; mf < 2; ++mf) {
        const int row = wm * 32 + mf * 16 + l15;
        if (ASPLIT) {
            aoffX[mf][0] = row * 128 + 16 * ((2 * g)     ^ pi8);
            aoffX[mf][1] = row * 128 + 16 * ((2 * g + 1) ^ pi8);
        } else {
            aoffH[mf] = row * 64 + 16 * (g ^ pi4);
        }
    }
#pragma unroll
    for (int nf = 0; nf < 4; ++nf) {
        const int row = wn * 64 + nf * 16 + l15;
        boff[nf] = row * 64 + 16 * (g ^ pi4);
    }

    f32x4 acc[2][4];
#pragma unroll
    for (int i = 0; i < 2; ++i)
#pragma unroll
        for (int j = 0; j < 4; ++j) acc[i][j] = (f32x4)0.f;

#define STAGE(buf, kt) do {                                             \
        _Pragma("unroll")                                               \
        for (int _j = 0; _j < 6; ++_j)                                  \
            GLOAD16(sp[_j] + (kt) * st[_j], smem[buf] + sd[_j]);        \
    } while (0)

#define COMPUTE(buf) do {                                                          \
        const char* _L = smem[buf];                                                \
        short8 _ah[2], _al[2], _bh[4], _bl[4];                                     \
        _Pragma("unroll")                                                          \
        for (int _nf = 0; _nf < 4; ++_nf) {                                        \
            _bh[_nf] = *(const short8*)(_L + 8192  + boff[_nf]);                   \
            _bl[_nf] = *(const short8*)(_L + 16384 + boff[_nf]);                   \
        }                                                                          \
        if (ASPLIT) {                                                              \
            _Pragma("unroll")                                                      \
            for (int _mf = 0; _mf < 2; ++_mf) {                                    \
                f32x4 _x0 = *(const f32x4*)(_L + aoffX[_mf][0]);                   \
                f32x4 _x1 = *(const f32x4*)(_L + aoffX[_mf][1]);                   \
                float _va[8];                                                      \
                *(f32x4*)_va = _x0; *(f32x4*)(_va + 4) = _x1;                      \
                _Pragma("unroll")                                                  \
                for (int _e = 0; _e < 8; ++_e) {                                   \
                    float _v = _va[_e];                                            \
                    __bf16 _h = (__bf16)_v;                                        \
                    _ah[_mf][_e] = __builtin_bit_cast(short, _h);                  \
                    _al[_mf][_e] = __builtin_bit_cast(short, (__bf16)(_v - (float)_h)); \
                }                                                                  \
            }                                                                      \
        } else {                                                                   \
            _Pragma("unroll")                                                      \
            for (int _mf = 0; _mf < 2; ++_mf) {                                    \
                _ah[_mf] = *(const short8*)(_L + aoffH[_mf]);                      \
                _al[_mf] = *(const short8*)(_L + 4096 + aoffH[_mf]);               \
            }                                                                      \
        }                                                                          \
        _Pragma("unroll")                                                          \
        for (int _mf = 0; _mf < 2; ++_mf)                                          \
        _Pragma("unroll")                                                          \
        for (int _nf = 0; _nf < 4; ++_nf) {                                        \
            acc[_mf][_nf] = __builtin_amdgcn_mfma_f32_16x16x32_bf16(_ah[_mf], _bh[_nf], acc[_mf][_nf], 0, 0, 0); \
            acc[_mf][_nf] = __builtin_amdgcn_mfma_f32_16x16x32_bf16(_al[_mf], _bh[_nf], acc[_mf][_nf], 0, 0, 0); \
            acc[_mf][_nf] = __builtin_amdgcn_mfma_f32_16x16x32_bf16(_ah[_mf], _bl[_nf], acc[_mf][_nf], 0, 0, 0); \
        }                                                                          \
    } while (0)

    // ---- triple-buffered counted-vmcnt pipeline over 32 k-tiles ----
    STAGE(0, 0);
    STAGE(1, 1);
    asm volatile("s_waitcnt vmcnt(6)" ::: "memory");
    __builtin_amdgcn_s_barrier();
    __builtin_amdgcn_sched_barrier(0);
#pragma unroll 3
    for (int t = 0; t < 30; ++t) {
        STAGE((t + 2) % 3, t + 2);
        COMPUTE(t % 3);
        asm volatile("s_waitcnt lgkmcnt(0)" ::: "memory");
        __builtin_amdgcn_sched_barrier(0);
        asm volatile("s_waitcnt vmcnt(6)" ::: "memory");
        __builtin_amdgcn_s_barrier();
        __builtin_amdgcn_sched_barrier(0);
    }
    COMPUTE(0);   // t=30
    asm volatile("s_waitcnt lgkmcnt(0)" ::: "memory");
    __builtin_amdgcn_sched_barrier(0);
    asm volatile("s_waitcnt vmcnt(0)" ::: "memory");
    __builtin_amdgcn_s_barrier();
    __builtin_amdgcn_sched_barrier(0);
    COMPUTE(1);   // t=31

    // ---- epilogue ----
    if (EPI == 0) {
#pragma unroll
        for (int mf = 0; mf < 2; ++mf)
#pragma unroll
        for (int nf = 0; nf < 4; ++nf)
#pragma unroll
        for (int jj = 0; jj < 4; ++jj) {
            const int row = bm * 64 + wm * 32 + mf * 16 + g * 4 + jj;
            const int col = bn * 128 + wn * 64 + nf * 16 + l15;
            const float v = tanhf(acc[mf][nf][jj]);
            const __bf16 h = (__bf16)v;
            Chi[(size_t)row * 1024 + col] = __builtin_bit_cast(unsigned short, h);
            Clo[(size_t)row * 1024 + col] =
                __builtin_bit_cast(unsigned short, (__bf16)(v - (float)h));
        }
    } else {
        float w[4];
#pragma unroll
        for (int nf = 0; nf < 4; ++nf)
            w[nf] = wout[bn * 128 + wn * 64 + nf * 16 + l15];
#pragma unroll
        for (int mf = 0; mf < 2; ++mf)
#pragma unroll
        for (int jj = 0; jj < 4; ++jj) {
            float v = 0.f;
#pragma unroll
            for (int nf = 0; nf < 4; ++nf)
                v += tanhf(acc[mf][nf][jj]) * w[nf];
            v += __shfl_xor(v, 1, 64);
            v += __shfl_xor(v, 2, 64);
            v += __shfl_xor(v, 4, 64);
            v += __shfl_xor(v, 8, 64);
            if (l15 == 0) {
                const int row = bm * 64 + wm * 32 + mf * 16 + g * 4 + jj;
                s_part[row * 16 + bn * 2 + wn] = v;
            }
        }
    }
#undef STAGE
#undef COMPUTE
}

// ---- finalize: s = sum(s_part), then faithful 27-path top-9 collapse -------
__global__ __launch_bounds__(256)
void pbcs_finalize(const float* __restrict__ s_part,
                   const float* __restrict__ soa_w, const float* __restrict__ soa_b,
                   const float* __restrict__ sob_w, const float* __restrict__ sob_b,
                   float* __restrict__ out, int Nrows)
{
    const int row  = blockIdx.x * 4 + (threadIdx.x >> 6);
    const int lane = threadIdx.x & 63;
    if (row >= Nrows) return;

    float part = (lane < 16) ? s_part[row * 16 + lane] : 0.f;
#pragma unroll
    for (int off = 32; off > 0; off >>= 1) part += __shfl_xor(part, off, 64);
    const float s = part;

    const float C7 = 0.8975979010256552f;   // 2*pi/7
    float tS = 0.f, tZ = 0.f, tN = 0.f;
    if (lane < 32) {
        const float aw = soa_w[lane];
        const float ab = soa_b[lane];
        const float bw = sob_w[lane];
        tS = bw * sinf(C7 * fmaf(aw,  s, ab));
        tZ = bw * sinf(C7 * ab);
        tN = bw * sinf(C7 * fmaf(aw, -s, ab));
    }
#pragma unroll
    for (int off = 32; off > 0; off >>= 1) {
        tS += __shfl_xor(tS, off, 64);
        tZ += __shfl_xor(tZ, off, 64);
        tN += __shfl_xor(tN, off, 64);
    }
    const float bb = sob_b[0];
    const float fS = tS + bb;
    const float f0 = tZ + bb;
    const float fN = tN + bb;

    // 27 paths: P[k] = {1,0,-1,0,0,0,-1,0,1}; tri q: (-pos, 0, +pos)
    const int j  = lane;
    const int kk = j / 3;
    const int q  = j - kk * 3;
    const int p  = ((0x101 >> kk) & 1) - ((0x044 >> kk) & 1);
    const int c  = (q == 0) ? -p : ((q == 2) ? p : 0);
    const float val = (float)c * s;
    const float sc  = (c == 0) ? f0 : ((c > 0) ? fS : fN);

    int rank = 0;
#pragma unroll 1
    for (int i = 0; i < 27; ++i) {
        const float sci = __shfl(sc, i, 64);
        rank += (sci > sc) || (sci == sc && i < j);
    }
    const float mx = fmaxf(fS, fmaxf(f0, fN));
    float e = (j < 27 && rank < 9) ? expf(sc - mx) : 0.f;
    float num = val * e;
    float den = e;
#pragma unroll
    for (int off = 32; off > 0; off >>= 1) {
        num += __shfl_xor(num, off, 64);
        den += __shfl_xor(den, off, 64);
    }
    if (lane == 0) out[row] = num / den;
}

extern "C" void kernel_launch(void* const* d_in, const int* in_sizes, int n_in,
                              void* d_out, int out_size, void* d_ws, size_t ws_size,
                              hipStream_t stream)
{
    const float* x     = (const float*)d_in[0];
    const float* W1    = (const float*)d_in[1];
    const float* W2    = (const float*)d_in[2];
    const float* Wout  = (const float*)d_in[3];
    const float* soa_w = (const float*)d_in[12];
    const float* soa_b = (const float*)d_in[13];
    const float* sob_w = (const float*)d_in[14];
    const float* sob_b = (const float*)d_in[15];

    const int Nr = 4096;
    char* ws = (char*)d_ws;
    unsigned short* W1hi = (unsigned short*)ws;                  // 2MB each
    unsigned short* W1lo = W1hi + (1u << 20);
    unsigned short* W2hi = W1hi + (2u << 20);
    unsigned short* W2lo = W1hi + (3u << 20);
    unsigned short* t1hi = (unsigned short*)(ws + (8u  << 20));  // 8MB
    unsigned short* t1lo = (unsigned short*)(ws + (16u << 20));  // 8MB
    float*          s_part = (float*)(ws + (24u << 20));         // 256KB

    pbcs_split<<<1024, 256, 0, stream>>>(W1, W1hi, W1lo);
    pbcs_split<<<1024, 256, 0, stream>>>(W2, W2hi, W2lo);

    dim3 grid(8, 64);   // (N/128, M/64) = 512 blocks
    pbcs_gemm<1, 0><<<grid, 256, 0, stream>>>(x, nullptr, nullptr, W1hi, W1lo,
                                              t1hi, t1lo, nullptr, nullptr);
    pbcs_gemm<0, 1><<<grid, 256, 0, stream>>>(nullptr, t1hi, t1lo, W2hi, W2lo,
                                              nullptr, nullptr, Wout, s_part);

    pbcs_finalize<<<Nr / 4, 256, 0, stream>>>(s_part, soa_w, soa_b, sob_w, sob_b,
                                              (float*)d_out, Nr);
}

// Round 4
// 56.373 us; speedup vs baseline: 5.3287x; 1.6346x over previous
//
#include <hip/hip_runtime.h>

// PathBundleChoiceScorer — reduced computation (verified rounds 1-3):
//   t1 = tanh(x @ W1^T); t2 = tanh(t1 @ W2^T); s[n] = dot(t2[n,:], Wout)
//   out[n] = top9-weighted collapse of {c_j*s}, c fixed {-1,0,+1} pattern.
// Round 4: single-product fp16 GEMMs (error ~2.8e-4 rel, below the measured
// 4.88e-4 f32-reassociation floor). 3x less MFMA + LDS traffic vs hi/lo split.
// 128x128 tile, 4 waves (64x64 each), K_STEP=64, double-buffered LDS with
// counted vmcnt(8), 2-way-free XOR swizzle, bijective XCD block swizzle.

typedef __attribute__((ext_vector_type(4))) float     f32x4;
typedef __attribute__((ext_vector_type(8))) _Float16  f16x8;

#define AS1 __attribute__((address_space(1)))
#define AS3 __attribute__((address_space(3)))
#define GLOAD16(gp, lp) \
    __builtin_amdgcn_global_load_lds((AS1 const void*)(gp), (AS3 void*)(lp), 16, 0, 0)

// ---- f32 -> f16 convert: x (4M elems), W1 (1M), W2 (1M); 8 elems/thread ----
__global__ __launch_bounds__(256)
void pbcs_cvt(const float* __restrict__ x,  _Float16* __restrict__ xo,
              const float* __restrict__ w1, _Float16* __restrict__ w1o,
              const float* __restrict__ w2, _Float16* __restrict__ w2o)
{
    const int b = blockIdx.x;
    const float* src; _Float16* dst; int idx;
    if (b < 2048)      { src = x;  dst = xo;  idx = b * 256 + threadIdx.x; }
    else if (b < 2560) { src = w1; dst = w1o; idx = (b - 2048) * 256 + threadIdx.x; }
    else               { src = w2; dst = w2o; idx = (b - 2560) * 256 + threadIdx.x; }
    const float4 v0 = ((const float4*)src)[idx * 2];
    const float4 v1 = ((const float4*)src)[idx * 2 + 1];
    f16x8 h;
    h[0] = (_Float16)v0.x; h[1] = (_Float16)v0.y;
    h[2] = (_Float16)v0.z; h[3] = (_Float16)v0.w;
    h[4] = (_Float16)v1.x; h[5] = (_Float16)v1.y;
    h[6] = (_Float16)v1.z; h[7] = (_Float16)v1.w;
    ((f16x8*)dst)[idx] = h;
}

// ---- fp16 MFMA GEMM:  C = A @ B^T, A [4096,1024] f16, B [1024,1024] f16 ----
// 256 threads = 4 waves (2m x 2n), wave tile 64x64, BK=64, 16 k-tiles.
// EPI=0: Cout = tanh(acc) as f16.  EPI=1: s_part += fused wout dot.
template<int EPI>
__global__ __launch_bounds__(256, 2)
void pbcs_gemm16(const _Float16* __restrict__ A, const _Float16* __restrict__ B,
                 _Float16* __restrict__ Cout, const float* __restrict__ wout,
                 float* __restrict__ s_part)
{
    __shared__ char smem[2][32768];   // [buf][ A 16K | B 16K ]

    const int tid  = threadIdx.x;
    const int lane = tid & 63;
    const int wid  = tid >> 6;
    const int wm   = wid >> 1;
    const int wn   = wid & 1;
    const int l15  = lane & 15;
    const int g    = lane >> 4;       // k-group 0..3

    // bijective XCD swizzle: XCD (= blk%8) owns a contiguous bm-stripe
    const int b  = blockIdx.x;                     // 0..255
    const int bm = (b & 7) * 4 + ((b >> 3) & 3);   // 0..31
    const int bn = b >> 5;                         // 0..7

    // ---- staging: 32 chunks of 1KB (16 A + 16 B), 8 per wave ----
    // chunk c covers rows c*8..c*8+7 (128B/row = 64 f16); linear LDS dest,
    // pre-swizzled global source (slot s holds k-group s^(row&7)).
    const char* aS[4]; const char* bS[4]; int aD[4], bD[4];
#pragma unroll
    for (int j = 0; j < 4; ++j) {
        const int c = wid * 4 + j;
        const int r = c * 8 + (lane >> 3), s = lane & 7;
        aS[j] = (const char*)A + (size_t)(bm * 128 + r) * 2048 + 16 * (s ^ (r & 7));
        aD[j] = c * 1024;
        bS[j] = (const char*)B + (size_t)(bn * 128 + r) * 2048 + 16 * (s ^ (r & 7));
        bD[j] = 16384 + c * 1024;
    }

    // ---- LDS read offsets (swizzled) ----
    int aoff[4][2], boff[4][2];
#pragma unroll
    for (int f = 0; f < 4; ++f) {
        const int ra = wm * 64 + f * 16 + l15;
        const int rb = wn * 64 + f * 16 + l15;
#pragma unroll
        for (int kh = 0; kh < 2; ++kh) {
            aoff[f][kh] = ra * 128 + 16 * (((kh << 2) | g) ^ (ra & 7));
            boff[f][kh] = 16384 + rb * 128 + 16 * (((kh << 2) | g) ^ (rb & 7));
        }
    }

    f32x4 acc[4][4];
#pragma unroll
    for (int i = 0; i < 4; ++i)
#pragma unroll
        for (int j = 0; j < 4; ++j) acc[i][j] = (f32x4)0.f;

#define STAGE(buf, kt) do {                                      \
        const int _ko = (kt) * 128;                              \
        _Pragma("unroll")                                        \
        for (int _j = 0; _j < 4; ++_j) {                         \
            GLOAD16(aS[_j] + _ko, smem[buf] + aD[_j]);           \
            GLOAD16(bS[_j] + _ko, smem[buf] + bD[_j]);           \
        }                                                        \
    } while (0)

#define COMPUTE(buf) do {                                                        \
        _Pragma("unroll")                                                        \
        for (int _kh = 0; _kh < 2; ++_kh) {                                      \
            f16x8 _a[4], _b[4];                                                  \
            _Pragma("unroll")                                                    \
            for (int _f = 0; _f < 4; ++_f) {                                     \
                _a[_f] = *(const f16x8*)(smem[buf] + aoff[_f][_kh]);             \
                _b[_f] = *(const f16x8*)(smem[buf] + boff[_f][_kh]);             \
            }                                                                    \
            _Pragma("unroll")                                                    \
            for (int _mf = 0; _mf < 4; ++_mf)                                    \
            _Pragma("unroll")                                                    \
            for (int _nf = 0; _nf < 4; ++_nf)                                    \
                acc[_mf][_nf] = __builtin_amdgcn_mfma_f32_16x16x32_f16(          \
                    _a[_mf], _b[_nf], acc[_mf][_nf], 0, 0, 0);                   \
        }                                                                        \
    } while (0)

    // ---- double-buffered counted-vmcnt loop over 16 k-tiles ----
    STAGE(0, 0);
    STAGE(1, 1);
#pragma unroll 1
    for (int t = 0; t < 15; ++t) {
        asm volatile("s_waitcnt vmcnt(8)" ::: "memory");  // k-tile t landed
        __builtin_amdgcn_s_barrier();
        __builtin_amdgcn_sched_barrier(0);
        COMPUTE(t & 1);
        asm volatile("s_waitcnt lgkmcnt(0)" ::: "memory");
        __builtin_amdgcn_sched_barrier(0);
        __builtin_amdgcn_s_barrier();                     // all reads of buf done
        if (t < 14) STAGE(t & 1, t + 2);
    }
    asm volatile("s_waitcnt vmcnt(0)" ::: "memory");
    __builtin_amdgcn_s_barrier();
    __builtin_amdgcn_sched_barrier(0);
    COMPUTE(1);   // t = 15

    // ---- epilogue ----
    if (EPI == 0) {
#pragma unroll
        for (int mf = 0; mf < 4; ++mf)
#pragma unroll
        for (int nf = 0; nf < 4; ++nf)
#pragma unroll
        for (int jj = 0; jj < 4; ++jj) {
            const int row = bm * 128 + wm * 64 + mf * 16 + g * 4 + jj;
            const int col = bn * 128 + wn * 64 + nf * 16 + l15;
            Cout[(size_t)row * 1024 + col] = (_Float16)tanhf(acc[mf][nf][jj]);
        }
    } else {
        float w[4];
#pragma unroll
        for (int nf = 0; nf < 4; ++nf)
            w[nf] = wout[bn * 128 + wn * 64 + nf * 16 + l15];
#pragma unroll
        for (int mf = 0; mf < 4; ++mf)
#pragma unroll
        for (int jj = 0; jj < 4; ++jj) {
            float v = 0.f;
#pragma unroll
            for (int nf = 0; nf < 4; ++nf)
                v += tanhf(acc[mf][nf][jj]) * w[nf];
            v += __shfl_xor(v, 1, 64);
            v += __shfl_xor(v, 2, 64);
            v += __shfl_xor(v, 4, 64);
            v += __shfl_xor(v, 8, 64);
            if (l15 == 0) {
                const int row = bm * 128 + wm * 64 + mf * 16 + g * 4 + jj;
                s_part[row * 16 + bn * 2 + wn] = v;
            }
        }
    }
#undef STAGE
#undef COMPUTE
}

// ---- finalize: s = sum(s_part), then faithful 27-path top-9 collapse -------
__global__ __launch_bounds__(256)
void pbcs_finalize(const float* __restrict__ s_part,
                   const float* __restrict__ soa_w, const float* __restrict__ soa_b,
                   const float* __restrict__ sob_w, const float* __restrict__ sob_b,
                   float* __restrict__ out, int Nrows)
{
    const int row  = blockIdx.x * 4 + (threadIdx.x >> 6);
    const int lane = threadIdx.x & 63;
    if (row >= Nrows) return;

    float part = (lane < 16) ? s_part[row * 16 + lane] : 0.f;
#pragma unroll
    for (int off = 32; off > 0; off >>= 1) part += __shfl_xor(part, off, 64);
    const float s = part;

    const float C7 = 0.8975979010256552f;   // 2*pi/7
    float tS = 0.f, tZ = 0.f, tN = 0.f;
    if (lane < 32) {
        const float aw = soa_w[lane];
        const float ab = soa_b[lane];
        const float bw = sob_w[lane];
        tS = bw * sinf(C7 * fmaf(aw,  s, ab));
        tZ = bw * sinf(C7 * ab);
        tN = bw * sinf(C7 * fmaf(aw, -s, ab));
    }
#pragma unroll
    for (int off = 32; off > 0; off >>= 1) {
        tS += __shfl_xor(tS, off, 64);
        tZ += __shfl_xor(tZ, off, 64);
        tN += __shfl_xor(tN, off, 64);
    }
    const float bb = sob_b[0];
    const float fS = tS + bb;
    const float f0 = tZ + bb;
    const float fN = tN + bb;

    // 27 paths: P[k] = {1,0,-1,0,0,0,-1,0,1}; tri q: (-pos, 0, +pos)
    const int j  = lane;
    const int kk = j / 3;
    const int q  = j - kk * 3;
    const int p  = ((0x101 >> kk) & 1) - ((0x044 >> kk) & 1);
    const int c  = (q == 0) ? -p : ((q == 2) ? p : 0);
    const float val = (float)c * s;
    const float sc  = (c == 0) ? f0 : ((c > 0) ? fS : fN);

    int rank = 0;
#pragma unroll 1
    for (int i = 0; i < 27; ++i) {
        const float sci = __shfl(sc, i, 64);
        rank += (sci > sc) || (sci == sc && i < j);
    }
    const float mx = fmaxf(fS, fmaxf(f0, fN));
    float e = (j < 27 && rank < 9) ? expf(sc - mx) : 0.f;
    float num = val * e;
    float den = e;
#pragma unroll
    for (int off = 32; off > 0; off >>= 1) {
        num += __shfl_xor(num, off, 64);
        den += __shfl_xor(den, off, 64);
    }
    if (lane == 0) out[row] = num / den;
}

extern "C" void kernel_launch(void* const* d_in, const int* in_sizes, int n_in,
                              void* d_out, int out_size, void* d_ws, size_t ws_size,
                              hipStream_t stream)
{
    const float* x     = (const float*)d_in[0];
    const float* W1    = (const float*)d_in[1];
    const float* W2    = (const float*)d_in[2];
    const float* Wout  = (const float*)d_in[3];
    const float* soa_w = (const float*)d_in[12];
    const float* soa_b = (const float*)d_in[13];
    const float* sob_w = (const float*)d_in[14];
    const float* sob_b = (const float*)d_in[15];

    const int Nr = 4096;
    char* ws = (char*)d_ws;
    _Float16* xf  = (_Float16*)ws;                    //  8MB  [4096,1024]
    _Float16* t1f = (_Float16*)(ws + (8u  << 20));    //  8MB  [4096,1024]
    _Float16* w1f = (_Float16*)(ws + (16u << 20));    //  2MB  [1024,1024]
    _Float16* w2f = (_Float16*)(ws + (18u << 20));    //  2MB  [1024,1024]
    float* s_part = (float*)(ws + (20u << 20));       //  256KB

    pbcs_cvt<<<3072, 256, 0, stream>>>(x, xf, W1, w1f, W2, w2f);

    pbcs_gemm16<0><<<256, 256, 0, stream>>>(xf,  w1f, t1f, nullptr, nullptr);
    pbcs_gemm16<1><<<256, 256, 0, stream>>>(t1f, w2f, nullptr, Wout, s_part);

    pbcs_finalize<<<Nr / 4, 256, 0, stream>>>(s_part, soa_w, soa_b, sob_w, sob_b,
                                              (float*)d_out, Nr);
}